// Round 1
// baseline (267.619 us; speedup 1.0000x reference)
//
#include <hip/hip_runtime.h>
#include <hip/hip_bf16.h>

// Linear1d: out[B,256] = (x[B,512] @ W[256,512]^T) / 8 + 0.1*bias
// Strategy: fold 1/8 into W, convert W to bf16 once (tiny kernel, L2-resident),
// then LDS-free streaming bf16-MFMA GEMM: x converted fp32->bf16 in registers.
// Memory floor ~202 MB => ~32 us at 6.3 TB/s.

typedef __bf16 bf16;
typedef __attribute__((ext_vector_type(8))) __bf16 bf16x8;
typedef __attribute__((ext_vector_type(4))) __bf16 bf16x4;
typedef __attribute__((ext_vector_type(4))) float f32x4;

#define BATCH_ 65536
#define KDIM   512
#define NDIM   256

__global__ __launch_bounds__(256) void wcvt_kernel(const float* __restrict__ w,
                                                   bf16* __restrict__ wb) {
    int i = (blockIdx.x * 256 + threadIdx.x) * 4;
    f32x4 v = *(const f32x4*)(w + i);
    bf16x4 o;
    o[0] = (bf16)(v.x * 0.125f);
    o[1] = (bf16)(v.y * 0.125f);
    o[2] = (bf16)(v.z * 0.125f);
    o[3] = (bf16)(v.w * 0.125f);
    *(bf16x4*)(wb + i) = o;
}

__global__ __launch_bounds__(256) void gemm_kernel(const float* __restrict__ x,
                                                   const bf16* __restrict__ wb,
                                                   const float* __restrict__ bias,
                                                   float* __restrict__ out) {
    const int lane = threadIdx.x & 63;
    const int wv   = threadIdx.x >> 6;   // wave 0..3 -> N quarter
    const int q    = lane >> 4;          // k-quad 0..3
    const int l16  = lane & 15;
    const long m0  = (long)blockIdx.x * 64;
    const int  n0  = wv * 64;

    // Per-lane base pointers.
    // A-operand layout (16x16x32): A[m = lane&15][k = q*8 + j]
    // B-operand layout:            B[k = q*8 + j][n = lane&15] == Wrow[n][k]
    const float* xp[4];
    const bf16*  wp[4];
#pragma unroll
    for (int t = 0; t < 4; ++t) {
        xp[t] = x  + (m0 + t * 16 + l16) * KDIM + q * 8;
        wp[t] = wb + (long)(n0 + t * 16 + l16) * KDIM + q * 8;
    }

    f32x4 acc[4][4];
#pragma unroll
    for (int i = 0; i < 4; ++i)
#pragma unroll
        for (int j = 0; j < 4; ++j)
            acc[i][j] = (f32x4)0.0f;

#pragma unroll 4
    for (int kc = 0; kc < 16; ++kc) {   // 16 k-chunks of 32
        bf16x8 a[4], b[4];
#pragma unroll
        for (int mt = 0; mt < 4; ++mt) {
            f32x4 lo = *(const f32x4*)(xp[mt] + kc * 32);
            f32x4 hi = *(const f32x4*)(xp[mt] + kc * 32 + 4);
            bf16x8 av;
            av[0] = (bf16)lo.x; av[1] = (bf16)lo.y;
            av[2] = (bf16)lo.z; av[3] = (bf16)lo.w;
            av[4] = (bf16)hi.x; av[5] = (bf16)hi.y;
            av[6] = (bf16)hi.z; av[7] = (bf16)hi.w;
            a[mt] = av;
        }
#pragma unroll
        for (int nt = 0; nt < 4; ++nt)
            b[nt] = *(const bf16x8*)(wp[nt] + kc * 32);
#pragma unroll
        for (int mt = 0; mt < 4; ++mt)
#pragma unroll
            for (int nt = 0; nt < 4; ++nt)
                acc[mt][nt] = __builtin_amdgcn_mfma_f32_16x16x32_bf16(
                    a[mt], b[nt], acc[mt][nt], 0, 0, 0);
    }

    // Epilogue. C/D layout: col = lane&15 (the B/n index), row = q*4 + reg.
    float bv[4];
#pragma unroll
    for (int nt = 0; nt < 4; ++nt)
        bv[nt] = 0.1f * bias[n0 + nt * 16 + l16];

#pragma unroll
    for (int mt = 0; mt < 4; ++mt)
#pragma unroll
        for (int nt = 0; nt < 4; ++nt)
#pragma unroll
            for (int r = 0; r < 4; ++r) {
                long row = m0 + mt * 16 + q * 4 + r;
                out[row * NDIM + n0 + nt * 16 + l16] = acc[mt][nt][r] + bv[nt];
            }
}

extern "C" void kernel_launch(void* const* d_in, const int* in_sizes, int n_in,
                              void* d_out, int out_size, void* d_ws, size_t ws_size,
                              hipStream_t stream) {
    const float* x    = (const float*)d_in[0];
    const float* w    = (const float*)d_in[1];
    const float* bias = (const float*)d_in[2];
    float* out = (float*)d_out;
    bf16* wb   = (bf16*)d_ws;   // 256*512*2 = 256 KB scratch

    wcvt_kernel<<<(NDIM * KDIM) / (256 * 4), 256, 0, stream>>>(w, wb);
    gemm_kernel<<<BATCH_ / 64, 256, 0, stream>>>(x, wb, bias, out);
}